// Round 6
// baseline (468.702 us; speedup 1.0000x reference)
//
#include <hip/hip_runtime.h>
#include <hip/hip_bf16.h>
#include <cstdint>

// Problem constants
// B=32, T=1024, C=512, COND_CH=256, L=252, S=128, M = B*T = 32768
// Inputs: fp32. Output d_out: fp32 (reference returns float32; the "bf16"
// in the harness label is the tolerance flavor, not the storage dtype).
// Internal GEMM traffic is bf16 (MFMA), fp32 accumulate.

typedef __attribute__((ext_vector_type(8))) short bf16x8;
typedef __attribute__((ext_vector_type(4))) float f32x4;
typedef __attribute__((ext_vector_type(8))) unsigned short u16x8;

__device__ __forceinline__ float bf2f(unsigned short u) {
  union { unsigned int i; float f; } x; x.i = ((unsigned int)u) << 16; return x.f;
}
__device__ __forceinline__ unsigned short f2bf(float f) {
  unsigned int u = __float_as_uint(f);
  unsigned int r = (u + 0x7FFFu + ((u >> 16) & 1u)) >> 16;
  return (unsigned short)r;
}

__device__ __forceinline__ float wave_sum(float v) {
#pragma unroll
  for (int m = 1; m < 64; m <<= 1) v += __shfl_xor(v, m, 64);
  return v;
}
__device__ __forceinline__ float wave_max(float v) {
#pragma unroll
  for (int m = 1; m < 64; m <<= 1) v = fmaxf(v, __shfl_xor(v, m, 64));
  return v;
}

// Stage 8 elements (16 B of bf16) into LDS; F32=1 converts fp32 source.
template <int F32>
__device__ __forceinline__ void stage16(const void* base, size_t eoff,
                                        unsigned short* dst) {
  if (F32) {
    const float* s = (const float*)base + eoff;
    f32x4 a0 = *(const f32x4*)s, a1 = *(const f32x4*)(s + 4);
    u16x8 t;
#pragma unroll
    for (int j = 0; j < 4; ++j) { t[j] = f2bf(a0[j]); t[j + 4] = f2bf(a1[j]); }
    *(u16x8*)dst = t;
  } else {
    *(u16x8*)dst = *(const u16x8*)((const unsigned short*)base + eoff);
  }
}

// ---------------------------------------------------------------------------
// prep: Ak[b,c] = sum_i pad[b,i]*Wk[c,i]; Av likewise; Wks/Wvs[c] = row sums
// pad[b,i] = cond_emb[b, (i-2) mod 252], i in [0,256)
// ---------------------------------------------------------------------------
__global__ __launch_bounds__(256) void prep(
    const float* __restrict__ cond_emb,
    const float* __restrict__ Wk,
    const float* __restrict__ Wv,
    float* __restrict__ Ak, float* __restrict__ Av,
    float* __restrict__ Wks, float* __restrict__ Wvs) {
  const int t = blockIdx.x * 256 + threadIdx.x;  // 0..16383
  const int b = t >> 9, c = t & 511;
  const float* ce = cond_emb + b * 252;
  float ak = 0.f, av = 0.f, ks = 0.f, vs = 0.f;
  for (int i = 0; i < 256; ++i) {
    int idx = i - 2; if (idx < 0) idx += 252; if (idx >= 252) idx -= 252;
    float p = ce[idx];
    float wk = Wk[c * 256 + i];
    float wv = Wv[c * 256 + i];
    ak += p * wk; av += p * wv; ks += wk; vs += wv;
  }
  Ak[b * 512 + c] = ak;
  Av[b * 512 + c] = av;
  if (b == 0) { Wks[c] = ks; Wvs[c] = vs; }
}

// ---------------------------------------------------------------------------
// BT GEMM: C[m,n] = sum_k A[m,k]*B[n,k] + bias[n], bf16 out, fp32 accum.
// EPI: 0 = bias, 1 = bias + exact GELU. AF32/BF32: operand is fp32 (converted
// to bf16 during staging). Tile 128x128, BK=64, 256 threads (4 waves, 2x2).
// ---------------------------------------------------------------------------
template <int EPI, int AF32, int BF32>
__global__ __launch_bounds__(256) void gemm_bt(
    const void* __restrict__ Aptr, const void* __restrict__ Bptr,
    const float* __restrict__ bias, unsigned short* __restrict__ Cc,
    int M, int N, int K) {
  __shared__ __align__(16) unsigned short lds_a[128 * 64];
  __shared__ __align__(16) unsigned short lds_b[128 * 64];
  const int nblk = N >> 7;
  const int bm = (int)blockIdx.x / nblk;
  const int bn = (int)blockIdx.x % nblk;
  const int tid = threadIdx.x;
  const int wave = tid >> 6;
  const int lane = tid & 63;
  const int wm = (wave >> 1) << 6;
  const int wn = (wave & 1) << 6;
  const int quad = lane >> 4;
  const int l16 = lane & 15;
  const int srow = lane >> 3;        // staging row within 8-row group
  const int scol = (lane & 7) << 3;  // staging col (elements)

  f32x4 acc[4][4] = {};

  const size_t abase = (size_t)(bm * 128) * (size_t)K;
  const size_t bbase = (size_t)(bn * 128) * (size_t)K;

  for (int k0 = 0; k0 < K; k0 += 64) {
#pragma unroll
    for (int j = 0; j < 4; ++j) {
      const int rr = wave * 32 + j * 8 + srow;  // tile row this lane stages
      stage16<AF32>(Aptr, abase + (size_t)rr * K + (k0 + scol), &lds_a[rr * 64 + scol]);
      stage16<BF32>(Bptr, bbase + (size_t)rr * K + (k0 + scol), &lds_b[rr * 64 + scol]);
    }
    __syncthreads();
#pragma unroll
    for (int kk = 0; kk < 64; kk += 32) {
      bf16x8 af[4], bfr[4];
#pragma unroll
      for (int i = 0; i < 4; ++i)
        af[i] = *(const bf16x8*)&lds_a[(wm + i * 16 + l16) * 64 + kk + quad * 8];
#pragma unroll
      for (int i = 0; i < 4; ++i)
        bfr[i] = *(const bf16x8*)&lds_b[(wn + i * 16 + l16) * 64 + kk + quad * 8];
#pragma unroll
      for (int mi = 0; mi < 4; ++mi)
#pragma unroll
        for (int ni = 0; ni < 4; ++ni)
          acc[mi][ni] = __builtin_amdgcn_mfma_f32_16x16x32_bf16(
              af[mi], bfr[ni], acc[mi][ni], 0, 0, 0);
    }
    __syncthreads();
  }

#pragma unroll
  for (int ni = 0; ni < 4; ++ni) {
    const int col = bn * 128 + wn + ni * 16 + l16;
    const float bsv = bias[col];
#pragma unroll
    for (int mi = 0; mi < 4; ++mi) {
#pragma unroll
      for (int r = 0; r < 4; ++r) {
        const int row = bm * 128 + wm + mi * 16 + quad * 4 + r;
        float v = acc[mi][ni][r] + bsv;
        if (EPI == 1) v = 0.5f * v * (1.0f + erff(v * 0.70710678118654752f));
        Cc[(size_t)row * N + col] = f2bf(v);
      }
    }
  }
}

// ---------------------------------------------------------------------------
// attn_ln: per q-row attention (collapsed to rank-2) + residual + LayerNorm1.
// One wave per row; lane handles 8 contiguous channels. IN-PLACE on qbuf
// (q -> query): each wave reads only its own row before writing it.
// ---------------------------------------------------------------------------
__global__ __launch_bounds__(256) void attn_ln(
    unsigned short* qbuf,
    const float* __restrict__ Ak, const float* __restrict__ Av,
    const float* __restrict__ Wks, const float* __restrict__ Wvs,
    const float* __restrict__ bk, const float* __restrict__ bv,
    const float* __restrict__ conv_w, const float* __restrict__ conv_b,
    const float* __restrict__ ln1w, const float* __restrict__ ln1b) {
  const int row = (int)((blockIdx.x * 256 + threadIdx.x) >> 6);  // 0..32767
  const int lane = threadIdx.x & 63;
  const int b = row >> 10;
  const int c0 = lane << 3;

  const u16x8 qv = *(const u16x8*)(qbuf + (size_t)row * 512 + c0);
  float qf[8];
#pragma unroll
  for (int j = 0; j < 8; ++j) qf[j] = bf2f(qv[j]);

  const f32x4* akp = (const f32x4*)(Ak + b * 512 + c0);
  const f32x4* avp = (const f32x4*)(Av + b * 512 + c0);
  const f32x4* ksp = (const f32x4*)(Wks + c0);
  const f32x4* vsp = (const f32x4*)(Wvs + c0);
  const f32x4* bkp = (const f32x4*)(bk + c0);
  const f32x4* bvp = (const f32x4*)(bv + c0);
  f32x4 ak0 = akp[0], ak1 = akp[1];
  f32x4 av0 = avp[0], av1 = avp[1];
  f32x4 ks0 = ksp[0], ks1 = ksp[1];
  f32x4 vs0 = vsp[0], vs1 = vsp[1];
  f32x4 bk0 = bkp[0], bk1 = bkp[1];
  f32x4 bv0 = bvp[0], bv1 = bvp[1];

  float u = 0.f, w = 0.f, z = 0.f;
#pragma unroll
  for (int j = 0; j < 8; ++j) {
    float a = (j < 4) ? ak0[j] : ak1[j - 4];
    float s = (j < 4) ? ks0[j] : ks1[j - 4];
    float bb = (j < 4) ? bk0[j] : bk1[j - 4];
    u += qf[j] * a;
    w += qf[j] * s;
    z += qf[j] * bb;
  }
  u = wave_sum(u); w = wave_sum(w); z = wave_sum(z);

  const float scale = 0.044194173824159216f;  // 1/sqrt(512)
  const float cw0 = conv_w[lane], cw1 = conv_w[lane + 64];
  const float cb0 = conv_b[lane], cb1 = conv_b[lane + 64];
  float s0 = scale * (cw0 * u + cb0 * w + z);
  float s1 = scale * (cw1 * u + cb1 * w + z);
  float mx = wave_max(fmaxf(s0, s1));
  float e0 = __expf(s0 - mx), e1 = __expf(s1 - mx);
  float se = wave_sum(e0 + e1);
  float sw = wave_sum(e0 * cw0 + e1 * cw1);
  float sb = wave_sum(e0 * cb0 + e1 * cb1);
  float alpha = sw / se, beta = sb / se;

  float y[8], sy = 0.f, syy = 0.f;
#pragma unroll
  for (int j = 0; j < 8; ++j) {
    float a = (j < 4) ? av0[j] : av1[j - 4];
    float s = (j < 4) ? vs0[j] : vs1[j - 4];
    float bb = (j < 4) ? bv0[j] : bv1[j - 4];
    y[j] = qf[j] + alpha * a + beta * s + bb;
    sy += y[j]; syy += y[j] * y[j];
  }
  sy = wave_sum(sy); syy = wave_sum(syy);
  float mu = sy * (1.0f / 512.0f);
  float var = syy * (1.0f / 512.0f) - mu * mu;
  float rstd = rsqrtf(var + 1e-5f);

  const f32x4* wp = (const f32x4*)(ln1w + c0);
  const f32x4* bp = (const f32x4*)(ln1b + c0);
  f32x4 w0 = wp[0], w1 = wp[1];
  f32x4 b0 = bp[0], b1 = bp[1];
  u16x8 outv;
#pragma unroll
  for (int j = 0; j < 8; ++j) {
    float ww = (j < 4) ? w0[j] : w1[j - 4];
    float bb = (j < 4) ? b0[j] : b1[j - 4];
    outv[j] = f2bf((y[j] - mu) * rstd * ww + bb);
  }
  *(u16x8*)(qbuf + (size_t)row * 512 + c0) = outv;
}

// ---------------------------------------------------------------------------
// ln2_res: out = LayerNorm2(query + ff) + x, FP32 out. One wave per row.
// ---------------------------------------------------------------------------
__global__ __launch_bounds__(256) void ln2_res(
    const unsigned short* __restrict__ query,
    const unsigned short* __restrict__ ff,
    const float* __restrict__ x,
    const float* __restrict__ ln2w, const float* __restrict__ ln2b,
    float* __restrict__ out) {
  const int row = (int)((blockIdx.x * 256 + threadIdx.x) >> 6);
  const int lane = threadIdx.x & 63;
  const int c0 = lane << 3;
  const size_t off = (size_t)row * 512 + c0;

  const u16x8 qv = *(const u16x8*)(query + off);
  const u16x8 fv = *(const u16x8*)(ff + off);
  const f32x4* xp = (const f32x4*)(x + off);
  f32x4 x0 = xp[0], x1 = xp[1];
  float y[8], sy = 0.f, syy = 0.f;
#pragma unroll
  for (int j = 0; j < 8; ++j) {
    y[j] = bf2f(qv[j]) + bf2f(fv[j]);
    sy += y[j]; syy += y[j] * y[j];
  }
  sy = wave_sum(sy); syy = wave_sum(syy);
  float mu = sy * (1.0f / 512.0f);
  float var = syy * (1.0f / 512.0f) - mu * mu;
  float rstd = rsqrtf(var + 1e-5f);

  const f32x4* wp = (const f32x4*)(ln2w + c0);
  const f32x4* bp = (const f32x4*)(ln2b + c0);
  f32x4 w0 = wp[0], w1 = wp[1];
  f32x4 b0 = bp[0], b1 = bp[1];
  f32x4 o0, o1;
#pragma unroll
  for (int j = 0; j < 4; ++j) {
    o0[j] = (y[j] - mu) * rstd * w0[j] + b0[j] + x0[j];
    o1[j] = (y[j + 4] - mu) * rstd * w1[j] + b1[j] + x1[j];
  }
  *(f32x4*)(out + off) = o0;
  *(f32x4*)(out + off + 4) = o1;
}

// ---------------------------------------------------------------------------

extern "C" void kernel_launch(void* const* d_in, const int* in_sizes, int n_in,
                              void* d_out, int out_size, void* d_ws, size_t ws_size,
                              hipStream_t stream) {
  const float* x        = (const float*)d_in[0];
  const float* cond_emb = (const float*)d_in[1];
  const float* Wq       = (const float*)d_in[2];
  const float* bq       = (const float*)d_in[3];
  const float* Wk       = (const float*)d_in[4];
  const float* bk       = (const float*)d_in[5];
  const float* Wv       = (const float*)d_in[6];
  const float* bv       = (const float*)d_in[7];
  const float* conv_w   = (const float*)d_in[8];
  const float* conv_b   = (const float*)d_in[9];
  const float* ln1w     = (const float*)d_in[10];
  const float* ln1b     = (const float*)d_in[11];
  const float* W1       = (const float*)d_in[12];
  const float* b1       = (const float*)d_in[13];
  const float* W2       = (const float*)d_in[14];
  const float* b2       = (const float*)d_in[15];
  const float* ln2w     = (const float*)d_in[16];
  const float* ln2b     = (const float*)d_in[17];
  float* out = (float*)d_out;

  const int M = 32768;  // B*T

  // Workspace layout (host-adaptive chunking of the FF over rows):
  //   [0,    64K)    Ak   fp32 32x512
  //   [64K,  128K)   Av   fp32 32x512
  //   [128K, 130K)   Wks  fp32 512
  //   [132K, 134K)   Wvs  fp32 512
  //   [1M,   33M)    q/query bf16 M x 512 (in-place transform)
  //   [33M,  ...)    h_chunk bf16 Mc x 1024 ; ff_chunk bf16 Mc x 512
  char* ws = (char*)d_ws;
  float* Ak  = (float*)(ws);
  float* Av  = (float*)(ws + 65536);
  float* Wks = (float*)(ws + 131072);
  float* Wvs = (float*)(ws + 135168);
  const size_t qoff = (size_t)1 << 20;
  const size_t qbytes = (size_t)M * 512 * 2;  // 32 MiB
  unsigned short* qbuf = (unsigned short*)(ws + qoff);

  int nc = 1;
  while (nc < 256) {
    size_t need = qoff + qbytes + (size_t)(M / nc) * 3072;  // h + ff chunk
    if (need <= ws_size) break;
    nc <<= 1;
  }
  const int Mc = M / nc;
  unsigned short* hbuf  = (unsigned short*)(ws + qoff + qbytes);
  unsigned short* ffbuf = (unsigned short*)(ws + qoff + qbytes + (size_t)Mc * 2048);

  prep<<<64, 256, 0, stream>>>(cond_emb, Wk, Wv, Ak, Av, Wks, Wvs);

  // q = x @ Wq^T + bq  (both operands fp32, converted during staging)
  gemm_bt<0, 1, 1><<<(M / 128) * (512 / 128), 256, 0, stream>>>(
      (const void*)x, (const void*)Wq, bq, qbuf, M, 512, 512);

  // query = LN1(q + attn_out), in place on qbuf
  attn_ln<<<M / 4, 256, 0, stream>>>(qbuf, Ak, Av, Wks, Wvs, bk, bv,
                                     conv_w, conv_b, ln1w, ln1b);

  // FF + LN2 + residual, chunked over rows to fit ws
  for (int c = 0; c < nc; ++c) {
    const size_t roff = (size_t)c * Mc;
    gemm_bt<1, 0, 1><<<(Mc / 128) * (1024 / 128), 256, 0, stream>>>(
        (const void*)(qbuf + roff * 512), (const void*)W1, b1, hbuf, Mc, 1024, 512);
    gemm_bt<0, 0, 1><<<(Mc / 128) * (512 / 128), 256, 0, stream>>>(
        (const void*)hbuf, (const void*)W2, b2, ffbuf, Mc, 512, 1024);
    ln2_res<<<Mc / 4, 256, 0, stream>>>(qbuf + roff * 512, ffbuf, x + roff * 512,
                                        ln2w, ln2b, out + roff * 512);
  }
}

// Round 7
// 391.129 us; speedup vs baseline: 1.1983x; 1.1983x over previous
//
#include <hip/hip_runtime.h>
#include <hip/hip_bf16.h>
#include <cstdint>

// Problem constants
// B=32, T=1024, C=512, COND_CH=256, L=252, S=128, M = B*T = 32768
// Inputs: fp32. Output d_out: fp32. Internal GEMM traffic bf16 (MFMA), fp32 accum.

typedef __attribute__((ext_vector_type(8))) short bf16x8;
typedef __attribute__((ext_vector_type(4))) float f32x4;
typedef __attribute__((ext_vector_type(8))) unsigned short u16x8;
typedef __attribute__((ext_vector_type(4))) unsigned short u16x4;

__device__ __forceinline__ float bf2f(unsigned short u) {
  union { unsigned int i; float f; } x; x.i = ((unsigned int)u) << 16; return x.f;
}
__device__ __forceinline__ unsigned short f2bf(float f) {
  unsigned int u = __float_as_uint(f);
  unsigned int r = (u + 0x7FFFu + ((u >> 16) & 1u)) >> 16;
  return (unsigned short)r;
}

__device__ __forceinline__ float wave_sum(float v) {
#pragma unroll
  for (int m = 1; m < 64; m <<= 1) v += __shfl_xor(v, m, 64);
  return v;
}
__device__ __forceinline__ float wave_max(float v) {
#pragma unroll
  for (int m = 1; m < 64; m <<= 1) v = fmaxf(v, __shfl_xor(v, m, 64));
  return v;
}

// async global->LDS, 16 B per lane; lds base must be wave-uniform.
__device__ __forceinline__ void async16(const void* g, void* l) {
  __builtin_amdgcn_global_load_lds(
      (const __attribute__((address_space(1))) void*)g,
      (__attribute__((address_space(3))) void*)l, 16, 0, 0);
}

// ---------------------------------------------------------------------------
// cvt: fp32 -> bf16, one 4-elem group per thread (n % 1024 == 0)
// ---------------------------------------------------------------------------
__global__ __launch_bounds__(256) void cvt(
    const float* __restrict__ in, unsigned short* __restrict__ o) {
  const int i = (blockIdx.x * 256 + threadIdx.x) * 4;
  f32x4 v = *(const f32x4*)(in + i);
  u16x4 t;
#pragma unroll
  for (int j = 0; j < 4; ++j) t[j] = f2bf(v[j]);
  *(u16x4*)(o + i) = t;
}

// ---------------------------------------------------------------------------
// prep: Ak[b,c] = sum_i pad[b,i]*Wk[c,i]; Av likewise; Wks/Wvs[c] = row sums
// pad[b,i] = cond_emb[b, (i-2) mod 252], i in [0,256)
// ---------------------------------------------------------------------------
__global__ __launch_bounds__(256) void prep(
    const float* __restrict__ cond_emb,
    const float* __restrict__ Wk,
    const float* __restrict__ Wv,
    float* __restrict__ Ak, float* __restrict__ Av,
    float* __restrict__ Wks, float* __restrict__ Wvs) {
  const int t = blockIdx.x * 256 + threadIdx.x;  // 0..16383
  const int b = t >> 9, c = t & 511;
  const float* ce = cond_emb + b * 252;
  float ak = 0.f, av = 0.f, ks = 0.f, vs = 0.f;
  for (int i = 0; i < 256; i += 4) {
    f32x4 wk = *(const f32x4*)(Wk + c * 256 + i);
    f32x4 wv = *(const f32x4*)(Wv + c * 256 + i);
#pragma unroll
    for (int j = 0; j < 4; ++j) {
      int idx = i + j - 2; if (idx < 0) idx += 252; if (idx >= 252) idx -= 252;
      float p = ce[idx];
      ak += p * wk[j]; av += p * wv[j]; ks += wk[j]; vs += wv[j];
    }
  }
  Ak[b * 512 + c] = ak;
  Av[b * 512 + c] = av;
  if (b == 0) { Wks[c] = ks; Wvs[c] = vs; }
}

// ---------------------------------------------------------------------------
// BT GEMM: C[m,n] = sum_k A[m,k]*B[n,k] + bias[n], bf16 out, fp32 accum.
// EPI: 0 = bias, 1 = bias + exact GELU.
// AF32: A is fp32 -> VALU convert staging; else async16 direct-to-LDS.
// B is always bf16 -> async16. Tile 128x128, BK=64, 256 thr (4 waves, 2x2).
// ---------------------------------------------------------------------------
template <int EPI, int AF32>
__global__ __launch_bounds__(256) void gemm_bt(
    const void* __restrict__ Aptr, const unsigned short* __restrict__ Bm,
    const float* __restrict__ bias, unsigned short* __restrict__ Cc,
    int M, int N, int K) {
  __shared__ __align__(16) unsigned short lds_a[128 * 64];
  __shared__ __align__(16) unsigned short lds_b[128 * 64];
  const int nblk = N >> 7;
  const int bm = (int)blockIdx.x / nblk;
  const int bn = (int)blockIdx.x % nblk;
  const int tid = threadIdx.x;
  const int wave = tid >> 6;
  const int lane = tid & 63;
  const int wm = (wave >> 1) << 6;
  const int wn = (wave & 1) << 6;
  const int quad = lane >> 4;
  const int l16 = lane & 15;
  const int srow = lane >> 3;        // staging row within 8-row group
  const int scol = (lane & 7) << 3;  // staging col (elements)

  f32x4 acc[4][4] = {};

  const size_t abase = (size_t)(bm * 128) * (size_t)K;
  const size_t bbase = (size_t)(bn * 128) * (size_t)K;

  for (int k0 = 0; k0 < K; k0 += 64) {
#pragma unroll
    for (int j = 0; j < 4; ++j) {
      const int r = wave * 32 + j * 8;  // wave-uniform row-group base
      if (AF32) {
        const float* src = (const float*)Aptr + abase + (size_t)(r + srow) * K + (k0 + scol);
        f32x4 a0 = *(const f32x4*)src, a1 = *(const f32x4*)(src + 4);
        u16x8 tv;
#pragma unroll
        for (int jj = 0; jj < 4; ++jj) { tv[jj] = f2bf(a0[jj]); tv[jj + 4] = f2bf(a1[jj]); }
        *(u16x8*)&lds_a[(r + srow) * 64 + scol] = tv;
      } else {
        async16((const unsigned short*)Aptr + abase + (size_t)(r + srow) * K + (k0 + scol),
                &lds_a[r * 64]);
      }
      async16(Bm + bbase + (size_t)(r + srow) * K + (k0 + scol), &lds_b[r * 64]);
    }
    __syncthreads();
#pragma unroll
    for (int kk = 0; kk < 64; kk += 32) {
      bf16x8 af[4], bfr[4];
#pragma unroll
      for (int i = 0; i < 4; ++i)
        af[i] = *(const bf16x8*)&lds_a[(wm + i * 16 + l16) * 64 + kk + quad * 8];
#pragma unroll
      for (int i = 0; i < 4; ++i)
        bfr[i] = *(const bf16x8*)&lds_b[(wn + i * 16 + l16) * 64 + kk + quad * 8];
#pragma unroll
      for (int mi = 0; mi < 4; ++mi)
#pragma unroll
        for (int ni = 0; ni < 4; ++ni)
          acc[mi][ni] = __builtin_amdgcn_mfma_f32_16x16x32_bf16(
              af[mi], bfr[ni], acc[mi][ni], 0, 0, 0);
    }
    __syncthreads();
  }

#pragma unroll
  for (int ni = 0; ni < 4; ++ni) {
    const int col = bn * 128 + wn + ni * 16 + l16;
    const float bsv = bias[col];
#pragma unroll
    for (int mi = 0; mi < 4; ++mi) {
#pragma unroll
      for (int r = 0; r < 4; ++r) {
        const int row = bm * 128 + wm + mi * 16 + quad * 4 + r;
        float v = acc[mi][ni][r] + bsv;
        if (EPI == 1) v = 0.5f * v * (1.0f + erff(v * 0.70710678118654752f));
        Cc[(size_t)row * N + col] = f2bf(v);
      }
    }
  }
}

// ---------------------------------------------------------------------------
// attn_ln: per q-row attention (collapsed to rank-2) + residual + LayerNorm1.
// One wave per row; lane handles 8 contiguous channels. IN-PLACE (q -> query).
// ---------------------------------------------------------------------------
__global__ __launch_bounds__(256) void attn_ln(
    unsigned short* qbuf,
    const float* __restrict__ Ak, const float* __restrict__ Av,
    const float* __restrict__ Wks, const float* __restrict__ Wvs,
    const float* __restrict__ bk, const float* __restrict__ bv,
    const float* __restrict__ conv_w, const float* __restrict__ conv_b,
    const float* __restrict__ ln1w, const float* __restrict__ ln1b) {
  const int row = (int)((blockIdx.x * 256 + threadIdx.x) >> 6);  // 0..32767
  const int lane = threadIdx.x & 63;
  const int b = row >> 10;
  const int c0 = lane << 3;

  const u16x8 qv = *(const u16x8*)(qbuf + (size_t)row * 512 + c0);
  float qf[8];
#pragma unroll
  for (int j = 0; j < 8; ++j) qf[j] = bf2f(qv[j]);

  const f32x4* akp = (const f32x4*)(Ak + b * 512 + c0);
  const f32x4* avp = (const f32x4*)(Av + b * 512 + c0);
  const f32x4* ksp = (const f32x4*)(Wks + c0);
  const f32x4* vsp = (const f32x4*)(Wvs + c0);
  const f32x4* bkp = (const f32x4*)(bk + c0);
  const f32x4* bvp = (const f32x4*)(bv + c0);
  f32x4 ak0 = akp[0], ak1 = akp[1];
  f32x4 av0 = avp[0], av1 = avp[1];
  f32x4 ks0 = ksp[0], ks1 = ksp[1];
  f32x4 vs0 = vsp[0], vs1 = vsp[1];
  f32x4 bk0 = bkp[0], bk1 = bkp[1];
  f32x4 bv0 = bvp[0], bv1 = bvp[1];

  float u = 0.f, w = 0.f, z = 0.f;
#pragma unroll
  for (int j = 0; j < 8; ++j) {
    float a = (j < 4) ? ak0[j] : ak1[j - 4];
    float s = (j < 4) ? ks0[j] : ks1[j - 4];
    float bb = (j < 4) ? bk0[j] : bk1[j - 4];
    u += qf[j] * a; w += qf[j] * s; z += qf[j] * bb;
  }
  u = wave_sum(u); w = wave_sum(w); z = wave_sum(z);

  const float scale = 0.044194173824159216f;  // 1/sqrt(512)
  const float cw0 = conv_w[lane], cw1 = conv_w[lane + 64];
  const float cb0 = conv_b[lane], cb1 = conv_b[lane + 64];
  float s0 = scale * (cw0 * u + cb0 * w + z);
  float s1 = scale * (cw1 * u + cb1 * w + z);
  float mx = wave_max(fmaxf(s0, s1));
  float e0 = __expf(s0 - mx), e1 = __expf(s1 - mx);
  float se = wave_sum(e0 + e1);
  float sw = wave_sum(e0 * cw0 + e1 * cw1);
  float sb = wave_sum(e0 * cb0 + e1 * cb1);
  float alpha = sw / se, beta = sb / se;

  float y[8], sy = 0.f, syy = 0.f;
#pragma unroll
  for (int j = 0; j < 8; ++j) {
    float a = (j < 4) ? av0[j] : av1[j - 4];
    float s = (j < 4) ? vs0[j] : vs1[j - 4];
    float bb = (j < 4) ? bv0[j] : bv1[j - 4];
    y[j] = qf[j] + alpha * a + beta * s + bb;
    sy += y[j]; syy += y[j] * y[j];
  }
  sy = wave_sum(sy); syy = wave_sum(syy);
  float mu = sy * (1.0f / 512.0f);
  float var = syy * (1.0f / 512.0f) - mu * mu;
  float rstd = rsqrtf(var + 1e-5f);

  const f32x4* wp = (const f32x4*)(ln1w + c0);
  const f32x4* bp = (const f32x4*)(ln1b + c0);
  f32x4 w0 = wp[0], w1 = wp[1];
  f32x4 b0 = bp[0], b1 = bp[1];
  u16x8 outv;
#pragma unroll
  for (int j = 0; j < 8; ++j) {
    float ww = (j < 4) ? w0[j] : w1[j - 4];
    float bb = (j < 4) ? b0[j] : b1[j - 4];
    outv[j] = f2bf((y[j] - mu) * rstd * ww + bb);
  }
  *(u16x8*)(qbuf + (size_t)row * 512 + c0) = outv;
}

// ---------------------------------------------------------------------------
// ln2_res: out = LayerNorm2(query + ff) + x, FP32 out. One wave per row.
// ---------------------------------------------------------------------------
__global__ __launch_bounds__(256) void ln2_res(
    const unsigned short* __restrict__ query,
    const unsigned short* __restrict__ ff,
    const float* __restrict__ x,
    const float* __restrict__ ln2w, const float* __restrict__ ln2b,
    float* __restrict__ out) {
  const int row = (int)((blockIdx.x * 256 + threadIdx.x) >> 6);
  const int lane = threadIdx.x & 63;
  const int c0 = lane << 3;
  const size_t off = (size_t)row * 512 + c0;

  const u16x8 qv = *(const u16x8*)(query + off);
  const u16x8 fv = *(const u16x8*)(ff + off);
  const f32x4* xp = (const f32x4*)(x + off);
  f32x4 x0 = xp[0], x1 = xp[1];
  float y[8], sy = 0.f, syy = 0.f;
#pragma unroll
  for (int j = 0; j < 8; ++j) {
    y[j] = bf2f(qv[j]) + bf2f(fv[j]);
    sy += y[j]; syy += y[j] * y[j];
  }
  sy = wave_sum(sy); syy = wave_sum(syy);
  float mu = sy * (1.0f / 512.0f);
  float var = syy * (1.0f / 512.0f) - mu * mu;
  float rstd = rsqrtf(var + 1e-5f);

  const f32x4* wp = (const f32x4*)(ln2w + c0);
  const f32x4* bp = (const f32x4*)(ln2b + c0);
  f32x4 w0 = wp[0], w1 = wp[1];
  f32x4 b0 = bp[0], b1 = bp[1];
  f32x4 o0, o1;
#pragma unroll
  for (int j = 0; j < 4; ++j) {
    o0[j] = (y[j] - mu) * rstd * w0[j] + b0[j] + x0[j];
    o1[j] = (y[j + 4] - mu) * rstd * w1[j] + b1[j] + x1[j];
  }
  *(f32x4*)(out + off) = o0;
  *(f32x4*)(out + off + 4) = o1;
}

// ---------------------------------------------------------------------------

extern "C" void kernel_launch(void* const* d_in, const int* in_sizes, int n_in,
                              void* d_out, int out_size, void* d_ws, size_t ws_size,
                              hipStream_t stream) {
  const float* x        = (const float*)d_in[0];
  const float* cond_emb = (const float*)d_in[1];
  const float* Wq       = (const float*)d_in[2];
  const float* bq       = (const float*)d_in[3];
  const float* Wk       = (const float*)d_in[4];
  const float* bk       = (const float*)d_in[5];
  const float* Wv       = (const float*)d_in[6];
  const float* bv       = (const float*)d_in[7];
  const float* conv_w   = (const float*)d_in[8];
  const float* conv_b   = (const float*)d_in[9];
  const float* ln1w     = (const float*)d_in[10];
  const float* ln1b     = (const float*)d_in[11];
  const float* W1       = (const float*)d_in[12];
  const float* b1       = (const float*)d_in[13];
  const float* W2       = (const float*)d_in[14];
  const float* b2       = (const float*)d_in[15];
  const float* ln2w     = (const float*)d_in[16];
  const float* ln2b     = (const float*)d_in[17];
  float* out = (float*)d_out;

  const int M = 32768;  // B*T

  // Workspace layout (all host-side arithmetic; deterministic per capture):
  //   smalls:  Ak(64K) Av(64K) Wks(2K+pad) Wvs(2K+pad)       -> 144 KiB
  //   Wqb bf16 512x512 (512K), W1b bf16 1024x512 (1M), W2b bf16 512x1024 (1M)
  //   qbuf bf16 Mx512 (32M)
  //   [optional] xb bf16 Mx512 (32M)  -- only if ws_size permits
  //   chunk: h bf16 Mcx1024 + ff bf16 Mcx512
  char* ws = (char*)d_ws;
  float* Ak  = (float*)(ws);
  float* Av  = (float*)(ws + 65536);
  float* Wks = (float*)(ws + 131072);
  float* Wvs = (float*)(ws + 135168);
  size_t off = 147456;
  unsigned short* Wqb = (unsigned short*)(ws + off); off += (size_t)512 * 512 * 2;
  unsigned short* W1b = (unsigned short*)(ws + off); off += (size_t)1024 * 512 * 2;
  unsigned short* W2b = (unsigned short*)(ws + off); off += (size_t)512 * 1024 * 2;
  unsigned short* qbuf = (unsigned short*)(ws + off); off += (size_t)M * 512 * 2;

  const size_t xb_bytes = (size_t)M * 512 * 2;
  const int use_xb = (ws_size >= off + xb_bytes + (size_t)(M / 8) * 3072) ? 1 : 0;
  unsigned short* xb = (unsigned short*)(ws + off);
  if (use_xb) off += xb_bytes;

  int nc = 1;
  while (nc < 256 && off + (size_t)(M / nc) * 3072 > ws_size) nc <<= 1;
  const int Mc = M / nc;
  unsigned short* hbuf  = (unsigned short*)(ws + off);
  unsigned short* ffbuf = (unsigned short*)(ws + off + (size_t)Mc * 2048);

  // Weight (and optionally x) conversion to bf16
  cvt<<<256, 256, 0, stream>>>(Wq, Wqb);
  cvt<<<512, 256, 0, stream>>>(W1, W1b);
  cvt<<<512, 256, 0, stream>>>(W2, W2b);
  if (use_xb) cvt<<<16384, 256, 0, stream>>>(x, xb);

  prep<<<64, 256, 0, stream>>>(cond_emb, Wk, Wv, Ak, Av, Wks, Wvs);

  // q = x @ Wq^T + bq
  if (use_xb)
    gemm_bt<0, 0><<<(M / 128) * (512 / 128), 256, 0, stream>>>(
        (const void*)xb, Wqb, bq, qbuf, M, 512, 512);
  else
    gemm_bt<0, 1><<<(M / 128) * (512 / 128), 256, 0, stream>>>(
        (const void*)x, Wqb, bq, qbuf, M, 512, 512);

  // query = LN1(q + attn_out), in place on qbuf
  attn_ln<<<M / 4, 256, 0, stream>>>(qbuf, Ak, Av, Wks, Wvs, bk, bv,
                                     conv_w, conv_b, ln1w, ln1b);

  // FF + LN2 + residual, chunked over rows to fit ws
  for (int c = 0; c < nc; ++c) {
    const size_t roff = (size_t)c * Mc;
    gemm_bt<1, 0><<<(Mc / 128) * (1024 / 128), 256, 0, stream>>>(
        (const void*)(qbuf + roff * 512), W1b, b1, hbuf, Mc, 1024, 512);
    gemm_bt<0, 0><<<(Mc / 128) * (512 / 128), 256, 0, stream>>>(
        (const void*)hbuf, W2b, b2, ffbuf, Mc, 512, 1024);
    ln2_res<<<Mc / 4, 256, 0, stream>>>(qbuf + roff * 512, ffbuf, x + roff * 512,
                                        ln2w, ln2b, out + roff * 512);
  }
}